// Round 8
// baseline (958.162 us; speedup 1.0000x reference)
//
#include <hip/hip_runtime.h>
#include <stdint.h>

typedef unsigned short u16;
typedef short v8s __attribute__((ext_vector_type(8)));
typedef float v4f __attribute__((ext_vector_type(4)));

typedef __attribute__((address_space(1))) uint32_t g_u32;
typedef __attribute__((address_space(3))) uint32_t l_u32;

__device__ __forceinline__ void glds16(const void* g, void* l) {
    __builtin_amdgcn_global_load_lds((const g_u32*)g, (l_u32*)l, 16, 0, 0);
}
__device__ __forceinline__ u16 f2b(float f) {
    uint32_t u = __builtin_bit_cast(uint32_t, f);
    u += 0x7FFFu + ((u >> 16) & 1u);
    return (u16)(u >> 16);
}
__device__ __forceinline__ uint32_t pk2(float a, float b) {
    uint32_t ua = __builtin_bit_cast(uint32_t, a) + 0x8000u;
    uint32_t ub = __builtin_bit_cast(uint32_t, b) + 0x8000u;
    return __builtin_amdgcn_perm(ub, ua, 0x07060302u);
}

#define MTOT  32768
#define HDIM  768
#define KDIM  2000
#define KPAD  2016

#define VMW(n) asm volatile("s_waitcnt vmcnt(" #n ")" ::: "memory")
#define LGKM0  asm volatile("s_waitcnt lgkmcnt(0)" ::: "memory")
#define BARX do { __builtin_amdgcn_s_barrier(); __builtin_amdgcn_sched_barrier(0); } while (0)

// ---------------- K0: weights -> bf16 (proj_w padded K 2000->2016 with zeros) -----------
__global__ __launch_bounds__(256) void cvt_weights(
    const float* __restrict__ pw, const float* __restrict__ nw,
    u16* __restrict__ Wb, u16* __restrict__ NWb)
{
    const int h = blockIdx.x;  // 768
    const float* src = pw + (size_t)h * KDIM;
    u16* dst = Wb + (size_t)h * KPAD;
    for (int k = threadIdx.x; k < KPAD; k += 256)
        dst[k] = (k < KDIM) ? f2b(src[k]) : (u16)0;
    const float* s2 = nw + (size_t)h * HDIM;
    u16* d2 = NWb + (size_t)h * HDIM;
    for (int k = threadIdx.x; k < HDIM; k += 256)
        d2[k] = f2b(s2[k]);
}

// ---------------- K0b: compact rows with negs==1 ----------------------------------------
__global__ __launch_bounds__(256) void compact_k(
    const int* __restrict__ negs, int* __restrict__ cmap,
    int* __restrict__ pos, int* __restrict__ cnt)
{
    __shared__ int pref[257];
    __shared__ int wsum[256];
    const int t = threadIdx.x;
    const int base = t * 128;
    int c = 0;
    for (int j = 0; j < 128; j++) c += (negs[base + j] == 1);
    wsum[t] = c;
    __syncthreads();
    if (t == 0) {
        int a = 0;
        for (int i = 0; i < 256; i++) { pref[i] = a; a += wsum[i]; }
        pref[256] = a;
        cnt[0] = a;
    }
    __syncthreads();
    int off = pref[t];
    for (int j = 0; j < 128; j++) {
        const int r = base + j;
        if (negs[r] == 1) { cmap[off] = r; pos[r] = off; off++; }
    }
    const int total = pref[256];
    for (int j = total + t; j < MTOT; j += 256) cmap[j] = 0;
}

// ---------------- K1: GEMM1  256x128 tile, BK=32, 4 waves, 3 blocks/CU ------------------
// Wave = 128m x 64n out: acc[8][4] (128 AGPR), af[8]+bf[4] = 12 ds_read_b128 -> 32 MFMA
// = 42.7 FLOP per LDS byte -- 2x every prior round (R1-R7 all ~21, LDS-BW-pinned at
// ~300us). LDS 48 KB -> 3 blocks/CU; 256 thr -> VGPR cap 512, no spill.
// A fp32 -> regs -> pk2 -> swizzled ds_write (R5-verified layout), read once from HBM
// per panel per n-tile. B bf16 via glds (R1-verified, 0 conflicts).
// Single barrier per K-step: all slot-(k+1) writes are AFTER BARX(k), which no wave
// passes until all finished compute(k-1) -- the only prior readers of that slot.
// Tail k>=2000: A clamped (garbage), Wb zero-padded -> 0.
__global__ __launch_bounds__(256) void gemm1(
    const float* __restrict__ A, const u16* __restrict__ Wb,
    const float* __restrict__ pb,
    const int* __restrict__ i_ty, const int* __restrict__ i_la,
    const int* __restrict__ i_op, const int* __restrict__ i_in, const int* __restrict__ i_ou,
    const float* __restrict__ te, const float* __restrict__ le, const float* __restrict__ oe,
    const float* __restrict__ ie, const float* __restrict__ ooe,
    u16* __restrict__ Xb)
{
    __shared__ __align__(16) u16 As[2][256 * 32];  // 2 x 16 KB bf16
    __shared__ __align__(16) u16 Bs[2][128 * 32];  // 2 x  8 KB bf16 (48 KB)

    const int bid = blockIdx.x;                    // 768 = 128 mt x 6 nt
    const int sw = (bid & 7) * 96 + (bid >> 3);    // XCD swizzle, bijective (768%8==0)
    const int mt = sw / 6, nt = sw % 6;
    const int m_base = mt * 256, n_base = nt * 128;

    const int tid = threadIdx.x;
    const int w = tid >> 6, lane = tid & 63;
    const int lm = lane & 15, quad = lane >> 4;
    const int wm = (w >> 1) * 128, wn = (w & 1) * 64;

    // A staging: wave covers rows [w*64, w*64+64) as 8 groups of 8 rows.
    // Lane: rsub = lane>>3 (row in group), csub = lane&7 (fp32 16B chunk, LINEAR src).
    const int rsub = lane >> 3, csub = lane & 7;
    const float* aPtr[8];
    int aW[8];
#pragma unroll
    for (int g = 0; g < 8; g++) {
        const int rl = w * 64 + g * 8 + rsub;
        aPtr[g] = A + (size_t)(m_base + rl) * KDIM;
        aW[g] = rl * 32 + (((csub >> 1) ^ ((rl >> 1) & 3)) << 3) + ((csub & 1) << 2);
    }
    // B staging: 2 glds (16 rows each); source chunk XOR-swizzled, dest linear.
    const u16* bSrc[2];
    int bDst[2];
#pragma unroll
    for (int t = 0; t < 2; t++) {
        const int rl = w * 32 + t * 16 + (lane >> 2);
        const int c = (lane & 3) ^ ((rl >> 1) & 3);
        bSrc[t] = Wb + (size_t)(n_base + rl) * KPAD + c * 8;
        bDst[t] = (w * 32 + t * 16) * 32;
    }

    v4f acc[8][4];
#pragma unroll
    for (int i = 0; i < 8; i++)
#pragma unroll
        for (int j = 0; j < 4; j++) acc[i][j] = (v4f){0.f, 0.f, 0.f, 0.f};

    auto ldA = [&](int kb, float4* r) {
        int k = kb * 32 + csub * 4;
        k = (k > 1996) ? 1996 : k;                 // tail clamp
#pragma unroll
        for (int g = 0; g < 8; g++) r[g] = *(const float4*)(aPtr[g] + k);
    };
    auto wrA = [&](const float4* r, int sl) {
#pragma unroll
        for (int g = 0; g < 8; g++) {
            uint2 p;
            p.x = pk2(r[g].x, r[g].y);
            p.y = pk2(r[g].z, r[g].w);
            *(uint2*)&As[sl][aW[g]] = p;
        }
    };
    auto stB = [&](int kb) {
        const int sl = kb & 1;
#pragma unroll
        for (int t = 0; t < 2; t++)
            glds16(bSrc[t] + kb * 32, &Bs[sl][bDst[t]]);
    };
    auto compute = [&](int kb) {
        const int sl = kb & 1;
        v8s af[8], bf[4];
#pragma unroll
        for (int i = 0; i < 8; i++) {
            const int r = wm + i * 16 + lm;
            af[i] = *(const v8s*)&As[sl][r * 32 + ((quad ^ ((r >> 1) & 3)) << 3)];
        }
#pragma unroll
        for (int j = 0; j < 4; j++) {
            const int r = wn + j * 16 + lm;
            bf[j] = *(const v8s*)&Bs[sl][r * 32 + ((quad ^ ((r >> 1) & 3)) << 3)];
        }
#pragma unroll
        for (int i = 0; i < 8; i++)
#pragma unroll
            for (int j = 0; j < 4; j++)
                acc[i][j] = __builtin_amdgcn_mfma_f32_16x16x32_bf16(af[i], bf[j], acc[i][j], 0, 0, 0);
    };

    // one K-step: slot k ready; write A(k+1), stage B(k+1), prefetch A(k+2) regs
    auto step = [&](int kb, const float4* cur, float4* nxt) {
        VMW(0);                       // B(k) glds + A(k+1) reg-loads all landed
        LGKM0;                        // my A(k) ds_writes committed
        BARX;                         // slot k globally ready; compute(k-1) done everywhere
        wrA(cur, (kb + 1) & 1);       // slot k+1: readers finished >=1 barrier ago
        stB(kb + 1);
        int kn = kb + 2; kn = (kn > 62) ? 62 : kn;
        ldA(kn, nxt);                 // deep reg prefetch (no LDS hazard)
        compute(kb);
    };

    // prologue: A(0)->slot0, B(0)->slot0, A(1)->regs
    float4 aP[8], aN[8];
    {
        float4 a0[8];
        ldA(0, a0);                   // 8 vm
        stB(0);                       // 2 vm
        ldA(1, aP);                   // 8 vm
        VMW(10);                      // a0 done
        wrA(a0, 0);
    }

    for (int kb = 0; kb < 62; kb += 2) {   // 62 steps, named ping-pong (no dyn idx)
        step(kb,     aP, aN);
        step(kb + 1, aN, aP);
    }
    VMW(0); LGKM0; BARX;
    compute(62);

    // epilogue: + proj_b + 5 table gathers, write bf16 x
#pragma unroll
    for (int i = 0; i < 8; i++) {
#pragma unroll
        for (int r = 0; r < 4; r++) {
            const int row = m_base + wm + i * 16 + quad * 4 + r;
            const int ty = i_ty[row], la = i_la[row], op = i_op[row];
            const int di = i_in[row], doo = i_ou[row];
            const float* pte = te + (size_t)ty * HDIM;
            const float* ple = le + (size_t)la * HDIM;
            const float* poe = oe + (size_t)op * HDIM;
            const float* pie = ie + (size_t)di * HDIM;
            const float* pou = ooe + (size_t)doo * HDIM;
            u16* orow = Xb + (size_t)row * HDIM;
#pragma unroll
            for (int j = 0; j < 4; j++) {
                const int col = n_base + wn + j * 16 + lm;
                float v = acc[i][j][r] + pb[col] + pte[col] + ple[col] + poe[col] + pie[col] + pou[col];
                orow[col] = f2b(v);
            }
        }
    }
}

// ---------------- K2: GEMM2 256x128 tile over COMPACTED rows, all-glds ------------------
// Same skeleton; A = Xb bf16 gathered through cmap (glds source addr is per-lane).
// 6 glds/wave/step. Blocks with m_base >= cnt exit; padded rows compute garbage
// into Yb[c >= cnt], never read.
__global__ __launch_bounds__(256) void gemm2(
    const u16* __restrict__ Xb, const u16* __restrict__ NWb,
    const float* __restrict__ nb, const int* __restrict__ cmap,
    const int* __restrict__ cnt, u16* __restrict__ Yb)
{
    __shared__ __align__(16) u16 As[2][256 * 32];  // 2 x 16 KB
    __shared__ __align__(16) u16 Bs[2][128 * 32];  // 2 x  8 KB

    const int bid = blockIdx.x;                    // 768 worst-case
    const int sw = (bid & 7) * 96 + (bid >> 3);
    const int mt = sw / 6, nt = sw % 6;
    const int m_base = mt * 256, n_base = nt * 128;
    if (m_base >= cnt[0]) return;

    const int tid = threadIdx.x;
    const int w = tid >> 6, lane = tid & 63;
    const int lm = lane & 15, quad = lane >> 4;
    const int wm = (w >> 1) * 128, wn = (w & 1) * 64;

    // A: 4 glds (16 rows each), rows gathered via cmap
    const u16* aSrc[4];
    int aDst[4];
#pragma unroll
    for (int t = 0; t < 4; t++) {
        const int rl = w * 64 + t * 16 + (lane >> 2);
        const int c = (lane & 3) ^ ((rl >> 1) & 3);
        aSrc[t] = Xb + (size_t)cmap[m_base + rl] * HDIM + c * 8;
        aDst[t] = (w * 64 + t * 16) * 32;
    }
    // B: 2 glds
    const u16* bSrc[2];
    int bDst[2];
#pragma unroll
    for (int t = 0; t < 2; t++) {
        const int rl = w * 32 + t * 16 + (lane >> 2);
        const int c = (lane & 3) ^ ((rl >> 1) & 3);
        bSrc[t] = NWb + (size_t)(n_base + rl) * HDIM + c * 8;
        bDst[t] = (w * 32 + t * 16) * 32;
    }

    v4f acc[8][4];
#pragma unroll
    for (int i = 0; i < 8; i++)
#pragma unroll
        for (int j = 0; j < 4; j++) acc[i][j] = (v4f){0.f, 0.f, 0.f, 0.f};

    auto stage = [&](int kb) {
        const int sl = kb & 1;
#pragma unroll
        for (int t = 0; t < 4; t++)
            glds16(aSrc[t] + kb * 32, &As[sl][aDst[t]]);
#pragma unroll
        for (int t = 0; t < 2; t++)
            glds16(bSrc[t] + kb * 32, &Bs[sl][bDst[t]]);
    };
    auto compute = [&](int kb) {
        const int sl = kb & 1;
        v8s af[8], bf[4];
#pragma unroll
        for (int i = 0; i < 8; i++) {
            const int r = wm + i * 16 + lm;
            af[i] = *(const v8s*)&As[sl][r * 32 + ((quad ^ ((r >> 1) & 3)) << 3)];
        }
#pragma unroll
        for (int j = 0; j < 4; j++) {
            const int r = wn + j * 16 + lm;
            bf[j] = *(const v8s*)&Bs[sl][r * 32 + ((quad ^ ((r >> 1) & 3)) << 3)];
        }
#pragma unroll
        for (int i = 0; i < 8; i++)
#pragma unroll
            for (int j = 0; j < 4; j++)
                acc[i][j] = __builtin_amdgcn_mfma_f32_16x16x32_bf16(af[i], bf[j], acc[i][j], 0, 0, 0);
    };

    stage(0);
    for (int kb = 0; kb < 23; ++kb) {       // 24 K-steps (768/32)
        VMW(0);                              // slot kb landed (mine)
        BARX;                                // landed everywhere; compute(kb-1) done
        stage(kb + 1);                       // slot kb+1: readers done >=1 barrier ago
        compute(kb);
    }
    VMW(0); BARX;
    compute(23);

#pragma unroll
    for (int i = 0; i < 8; i++) {
#pragma unroll
        for (int r = 0; r < 4; r++) {
            const int crow = m_base + wm + i * 16 + quad * 4 + r;
            u16* orow = Yb + (size_t)crow * HDIM;
#pragma unroll
            for (int j = 0; j < 4; j++) {
                const int col = n_base + wn + j * 16 + lm;
                orow[col] = f2b(acc[i][j][r] + nb[col]);
            }
        }
    }
}

// ---------------- K3: select (negs, via pos map) + LayerNorm, one wave per row ----------
__global__ __launch_bounds__(256) void ln_k(
    const u16* __restrict__ Xb, const u16* __restrict__ Yb,
    const int* __restrict__ negs, const int* __restrict__ pos,
    const float* __restrict__ g, const float* __restrict__ b,
    float* __restrict__ out)
{
    const int w = threadIdx.x >> 6, lane = threadIdx.x & 63;
    const int row = blockIdx.x * 4 + w;
    const u16* src = (negs[row] == 1) ? (Yb + (size_t)pos[row] * HDIM)
                                      : (Xb + (size_t)row * HDIM);

    float v[12];
    float s = 0.f, ss = 0.f;
#pragma unroll
    for (int p = 0; p < 3; p++) {
        uint2 u = *(const uint2*)(src + (p * 64 + lane) * 4);
        float f0 = __builtin_bit_cast(float, u.x << 16);
        float f1 = __builtin_bit_cast(float, u.x & 0xFFFF0000u);
        float f2 = __builtin_bit_cast(float, u.y << 16);
        float f3 = __builtin_bit_cast(float, u.y & 0xFFFF0000u);
        v[p * 4 + 0] = f0; v[p * 4 + 1] = f1; v[p * 4 + 2] = f2; v[p * 4 + 3] = f3;
        s += f0 + f1 + f2 + f3;
        ss += f0 * f0 + f1 * f1 + f2 * f2 + f3 * f3;
    }
#pragma unroll
    for (int off = 1; off < 64; off <<= 1) {
        s += __shfl_xor(s, off);
        ss += __shfl_xor(ss, off);
    }
    const float mean = s * (1.f / (float)HDIM);
    const float var = ss * (1.f / (float)HDIM) - mean * mean;
    const float rs = rsqrtf(var + 1e-12f);

    float* orow = out + (size_t)row * HDIM;
#pragma unroll
    for (int p = 0; p < 3; p++) {
        const int c0 = (p * 64 + lane) * 4;
        float4 gg = *(const float4*)(g + c0);
        float4 bb = *(const float4*)(b + c0);
        float4 o;
        o.x = (v[p * 4 + 0] - mean) * rs * gg.x + bb.x;
        o.y = (v[p * 4 + 1] - mean) * rs * gg.y + bb.y;
        o.z = (v[p * 4 + 2] - mean) * rs * gg.z + bb.z;
        o.w = (v[p * 4 + 3] - mean) * rs * gg.w + bb.w;
        *(float4*)(orow + c0) = o;
    }
}

extern "C" void kernel_launch(void* const* d_in, const int* in_sizes, int n_in,
                              void* d_out, int out_size, void* d_ws, size_t ws_size,
                              hipStream_t stream) {
    (void)in_sizes; (void)n_in; (void)out_size; (void)ws_size;
    const float* A   = (const float*)d_in[0];
    const int* i_ty  = (const int*)d_in[1];
    const int* i_la  = (const int*)d_in[2];
    const int* i_op  = (const int*)d_in[3];
    const int* i_in  = (const int*)d_in[4];
    const int* i_ou  = (const int*)d_in[5];
    const int* negs  = (const int*)d_in[6];
    const float* te  = (const float*)d_in[7];
    const float* le  = (const float*)d_in[8];
    const float* oe  = (const float*)d_in[9];
    const float* ie  = (const float*)d_in[10];
    const float* ooe = (const float*)d_in[11];
    const float* pw  = (const float*)d_in[12];
    const float* pb  = (const float*)d_in[13];
    const float* nw  = (const float*)d_in[14];
    const float* nb  = (const float*)d_in[15];
    const float* lng = (const float*)d_in[16];
    const float* lnb = (const float*)d_in[17];
    float* out = (float*)d_out;

    // workspace layout (~100.3 MiB)
    char* ws = (char*)d_ws;
    u16* Wb  = (u16*)ws;                                    // 768*2016*2  = 3,096,576
    u16* NWb = (u16*)(ws + 3096576);                        // 768*768*2   = 1,179,648
    u16* Xb  = (u16*)(ws + 4276224);                        // 32768*768*2 = 50,331,648
    u16* Yb  = (u16*)(ws + 4276224 + 50331648);             // 50,331,648
    int* cmap = (int*)(ws + 4276224 + 100663296);           // 131,072
    int* pos  = (int*)(ws + 4276224 + 100663296 + 131072);  // 131,072
    int* cnt  = (int*)(ws + 4276224 + 100663296 + 262144);  // 128

    cvt_weights<<<768, 256, 0, stream>>>(pw, nw, Wb, NWb);
    compact_k<<<1, 256, 0, stream>>>(negs, cmap, pos, cnt);
    gemm1<<<768, 256, 0, stream>>>(A, Wb, pb, i_ty, i_la, i_op, i_in, i_ou,
                                   te, le, oe, ie, ooe, Xb);
    gemm2<<<768, 256, 0, stream>>>(Xb, NWb, nb, cmap, cnt, Yb);
    ln_k<<<8192, 256, 0, stream>>>(Xb, Yb, negs, pos, lng, lnb, out);
}